// Round 1
// baseline (268.337 us; speedup 1.0000x reference)
//
#include <hip/hip_runtime.h>
#include <float.h>
#include <math.h>

// ---- workspace layout (floats) ----
#define PER_BRANCH 23040
#define O_CNT     0        // 64
#define O_PSUM    64       // 192
#define O_BIAS1   256      // 2048
#define O_SUM1    2304     // 32
#define O_SUMSQ1  2336     // 32
#define O_SEGMAX1 2368     // 2048
#define O_SEGMIN1 4416     // 2048
#define O_AB1     6464     // 64 (a1[32], b1[32])
#define O_HSEG    6528     // 4096
#define O_SUM2    10624    // 64
#define O_SUMSQ2  10688    // 64
#define O_SEGMAX2 10752    // 4096
#define O_SEGMIN2 14848    // 4096
#define O_PMAX    18944    // 4096
// shared region
#define O_U       (2*PER_BRANCH)   // 192
#define O_C32     (O_U+192)        // 32
#define O_D       (O_C32+32)       // 65536
#define O_HMLP    (O_D+65536)      // 4096

#define S1 4
#define S2 4
#define S3 8
#define T3 64

__device__ __forceinline__ int lower_bound_i(const int* a, int n, int v) {
    int lo = 0, hi = n;
    while (lo < hi) { int mid = (lo + hi) >> 1; if (a[mid] < v) lo = mid + 1; else hi = mid; }
    return lo;
}
__device__ __forceinline__ void atomicMaxF(float* a, float v) {
    if (v >= 0.f) atomicMax((int*)a, __float_as_int(v));
    else atomicMin((unsigned int*)a, (unsigned int)__float_as_int(v));
}
__device__ __forceinline__ void atomicMinF(float* a, float v) {
    if (v >= 0.f) atomicMin((int*)a, __float_as_int(v));
    else atomicMax((unsigned int*)a, (unsigned int)__float_as_int(v));
}
__device__ __forceinline__ bool is_valid(float p0, float p1) {
    return (floorf((p0 + 3.f) / 6.f) == 0.f) && (floorf((p1 + 3.f) / 6.f) == 0.f);
}

__global__ void initKernel(float* ws) {
    int t = blockIdx.x * blockDim.x + threadIdx.x;
    float* base = ws + (size_t)blockIdx.y * PER_BRANCH;
    if (t < 256) base[t] = 0.f;                                    // cnt + psum
    else if (t >= O_SUM1   && t < O_SUM1 + 64)    base[t] = 0.f;   // sum1+sumsq1
    else if (t >= O_SUM2   && t < O_SUM2 + 128)   base[t] = 0.f;   // sum2+sumsq2
    else if (t >= O_SEGMAX1 && t < O_SEGMAX1+2048) base[t] = -FLT_MAX;
    else if (t >= O_SEGMIN1 && t < O_SEGMIN1+2048) base[t] =  FLT_MAX;
    else if (t >= O_SEGMAX2 && t < O_SEGMAX2+4096) base[t] = -FLT_MAX;
    else if (t >= O_SEGMIN2 && t < O_SEGMIN2+4096) base[t] =  FLT_MAX;
}

__global__ void foldW1Kernel(const float* __restrict__ W1, float* ws) {
    int c = threadIdx.x;
    if (c >= 32) return;
    float* U = ws + O_U;
    U[0*32+c] = W1[0*32+c] + W1[3*32+c] + W1[6*32+c];
    U[1*32+c] = W1[1*32+c] + W1[4*32+c] + W1[7*32+c];
    U[2*32+c] = W1[2*32+c] + W1[5*32+c] + W1[8*32+c];
    U[3*32+c] = W1[9*32+c];
    U[4*32+c] = W1[10*32+c];
    U[5*32+c] = W1[11*32+c];
    ws[O_C32+c] = 3.f * (W1[6*32+c] + W1[7*32+c]);
}

__global__ __launch_bounds__(256) void pass1Kernel(const float* __restrict__ x0, const int* __restrict__ bt0,
                                                   const float* __restrict__ x1, const int* __restrict__ bt1,
                                                   int N, float* ws) {
    int br = blockIdx.y;
    const float* x = br ? x1 : x0;
    const int* batch = br ? bt1 : bt0;
    float* base = ws + (size_t)br * PER_BRANCH;
    int b = blockIdx.x / S1, s = blockIdx.x % S1;
    int lo = lower_bound_i(batch, N, b), hi = lower_bound_i(batch, N, b + 1);
    int chunk = (hi - lo + S1 - 1) / S1;
    int beg = lo + s * chunk, end = min(hi, beg + chunk);
    float c = 0, sx = 0, sy = 0, sz = 0;
    for (int i = beg + (int)threadIdx.x; i < end; i += blockDim.x) {
        const float* p = x + (size_t)i * 6;
        float p0 = p[0], p1 = p[1], p2 = p[2];
        if (is_valid(p0, p1)) { c += 1.f; sx += p0; sy += p1; sz += p2; }
    }
    for (int off = 32; off; off >>= 1) {
        c  += __shfl_down(c, off);  sx += __shfl_down(sx, off);
        sy += __shfl_down(sy, off); sz += __shfl_down(sz, off);
    }
    __shared__ float red[4][4];
    int wid = threadIdx.x >> 6, lane = threadIdx.x & 63;
    if (lane == 0) { red[wid][0]=c; red[wid][1]=sx; red[wid][2]=sy; red[wid][3]=sz; }
    __syncthreads();
    if (threadIdx.x == 0) {
        float tc=0, tx=0, ty=0, tz=0;
        for (int w = 0; w < 4; w++) { tc+=red[w][0]; tx+=red[w][1]; ty+=red[w][2]; tz+=red[w][3]; }
        atomicAdd(base + O_CNT + b, tc);
        atomicAdd(base + O_PSUM + b*3 + 0, tx);
        atomicAdd(base + O_PSUM + b*3 + 1, ty);
        atomicAdd(base + O_PSUM + b*3 + 2, tz);
    }
}

__global__ void bias1Kernel(const float* __restrict__ W1, float* ws) {
    int br = blockIdx.y; float* base = ws + (size_t)br * PER_BRANCH;
    int b = blockIdx.x, c = threadIdx.x;
    float cn = fmaxf(base[O_CNT + b], 1.f);
    float mx = base[O_PSUM + b*3 + 0] / cn;
    float my = base[O_PSUM + b*3 + 1] / cn;
    float mz = base[O_PSUM + b*3 + 2] / cn;
    base[O_BIAS1 + b*32 + c] = ws[O_C32 + c] - mx*W1[3*32+c] - my*W1[4*32+c] - mz*W1[5*32+c];
}

__global__ __launch_bounds__(256) void pass2Kernel(const float* __restrict__ x0, const int* __restrict__ bt0,
                                                   const float* __restrict__ x1, const int* __restrict__ bt1,
                                                   int N, float* ws) {
    int br = blockIdx.y;
    const float* x = br ? x1 : x0;
    const int* batch = br ? bt1 : bt0;
    float* base = ws + (size_t)br * PER_BRANCH;
    int b = blockIdx.x / S2, s = blockIdx.x % S2;
    int lo = lower_bound_i(batch, N, b), hi = lower_bound_i(batch, N, b + 1);
    int chunk = (hi - lo + S2 - 1) / S2;
    int beg = lo + s * chunk, end = min(hi, beg + chunk);

    __shared__ float Ul[6][32], b1l[32];
    int t = threadIdx.x;
    if (t < 192) Ul[t / 32][t & 31] = ws[O_U + t];
    if (t < 32)  b1l[t] = base[O_BIAS1 + b*32 + t];
    __syncthreads();

    int c = t & 31, g = t >> 5;   // 8 point-groups x 32 channels
    float u0=Ul[0][c], u1=Ul[1][c], u2=Ul[2][c], u3=Ul[3][c], u4=Ul[4][c], u5=Ul[5][c], bb=b1l[c];
    float s1 = 0, ss = 0, mx = -FLT_MAX, mn = FLT_MAX;
    for (int i = beg + g; i < end; i += 8) {
        const float* p = x + (size_t)i * 6;
        float p0=p[0], p1=p[1], p2=p[2], e0=p[3], e1=p[4], e2=p[5];
        if (is_valid(p0, p1)) {
            float h = fmaf(p0,u0, fmaf(p1,u1, fmaf(p2,u2, fmaf(e0,u3, fmaf(e1,u4, fmaf(e2,u5, bb))))));
            s1 += h; ss += h*h; mx = fmaxf(mx, h); mn = fminf(mn, h);
        }
    }
    __shared__ float red[8][32];
    red[g][c] = s1; __syncthreads();
    if (g == 0) { float v=0; for (int k=0;k<8;k++) v += red[k][c]; atomicAdd(base+O_SUM1+c, v); }
    __syncthreads();
    red[g][c] = ss; __syncthreads();
    if (g == 0) { float v=0; for (int k=0;k<8;k++) v += red[k][c]; atomicAdd(base+O_SUMSQ1+c, v); }
    __syncthreads();
    red[g][c] = mx; __syncthreads();
    if (g == 0) { float v=-FLT_MAX; for (int k=0;k<8;k++) v = fmaxf(v, red[k][c]);
                  if (v > -FLT_MAX) atomicMaxF(base+O_SEGMAX1+b*32+c, v); }
    __syncthreads();
    red[g][c] = mn; __syncthreads();
    if (g == 0) { float v=FLT_MAX; for (int k=0;k<8;k++) v = fminf(v, red[k][c]);
                  if (v < FLT_MAX) atomicMinF(base+O_SEGMIN1+b*32+c, v); }
}

// fuses BN1 coefficient computation + per-segment hmax @ W2[32:]
__global__ void hsegKernel(const float* __restrict__ W2, const float* __restrict__ g1,
                           const float* __restrict__ bb1, float* ws) {
    int br = blockIdx.y; float* base = ws + (size_t)br * PER_BRANCH;
    int b = blockIdx.x, t = threadIdx.x;   // 64 threads
    __shared__ float hmaxv[32];
    float tot = 0.f;
    for (int k = 0; k < 64; k++) tot += base[O_CNT + k];
    float n = fmaxf(tot, 1.f);
    if (t < 32) {
        float m = base[O_SUM1 + t] / n;
        float v = base[O_SUMSQ1 + t] / n - m*m;
        float a = g1[t] * rsqrtf(v + 0.001f);
        float bv = bb1[t] - m*a;
        if (b == 0) { base[O_AB1 + t] = a; base[O_AB1 + 32 + t] = bv; }
        float hm = 0.f;
        if (base[O_CNT + b] > 0.f) {
            float pre = (a >= 0.f) ? base[O_SEGMAX1 + b*32 + t] : base[O_SEGMIN1 + b*32 + t];
            hm = fmaxf(a*pre + bv, 0.f);
        }
        hmaxv[t] = hm;
    }
    __syncthreads();
    float acc = 0.f;
    for (int k = 0; k < 32; k++) acc = fmaf(hmaxv[k], W2[(32 + k)*64 + t], acc);
    base[O_HSEG + b*64 + t] = acc;
}

__global__ __launch_bounds__(256) void pass3Kernel(const float* __restrict__ x0, const int* __restrict__ bt0,
                                                   const float* __restrict__ x1, const int* __restrict__ bt1,
                                                   int N, const float* __restrict__ W2, float* ws) {
    int br = blockIdx.y;
    const float* x = br ? x1 : x0;
    const int* batch = br ? bt1 : bt0;
    float* base = ws + (size_t)br * PER_BRANCH;
    int b = blockIdx.x / S3, s = blockIdx.x % S3;
    int lo = lower_bound_i(batch, N, b), hi = lower_bound_i(batch, N, b + 1);
    int chunk = (hi - lo + S3 - 1) / S3;
    int beg = lo + s * chunk, end = min(hi, beg + chunk);

    __shared__ float Ul[6][32], b1l[32], a1l[32], bb1l[32], hsegl[64];
    __shared__ float hh[T3][32];
    __shared__ float flagv[T3];
    __shared__ float red2[4][64];
    int t = threadIdx.x;
    if (t < 192) Ul[t / 32][t & 31] = ws[O_U + t];
    if (t < 32) { b1l[t] = base[O_BIAS1 + b*32 + t]; a1l[t] = base[O_AB1 + t]; bb1l[t] = base[O_AB1 + 32 + t]; }
    if (t < 64) hsegl[t] = base[O_HSEG + b*64 + t];
    __syncthreads();

    int c = t & 31, g = t >> 5;   // stage1: 8 groups
    int o = t & 63, q = t >> 6;   // stage2: 4 groups
    float w2c[32];
    #pragma unroll
    for (int k = 0; k < 32; k++) w2c[k] = W2[k*64 + o];

    float u0=Ul[0][c], u1=Ul[1][c], u2=Ul[2][c], u3=Ul[3][c], u4=Ul[4][c], u5=Ul[5][c];
    float bb=b1l[c], a1=a1l[c], ab=bb1l[c], hs=hsegl[o];
    float s2 = 0, ss2 = 0, mx2 = -FLT_MAX, mn2 = FLT_MAX;

    for (int tile = beg; tile < end; tile += T3) {
        int npts = min(T3, end - tile);
        for (int p = g; p < npts; p += 8) {
            const float* px = x + (size_t)(tile + p) * 6;
            float p0=px[0], p1=px[1], p2=px[2], e0=px[3], e1=px[4], e2=px[5];
            float h1 = fmaf(p0,u0, fmaf(p1,u1, fmaf(p2,u2, fmaf(e0,u3, fmaf(e1,u4, fmaf(e2,u5, bb))))));
            hh[p][c] = fmaxf(a1*h1 + ab, 0.f);
            if (c == 0) flagv[p] = is_valid(p0, p1) ? 1.f : 0.f;
        }
        __syncthreads();
        int pend = min(npts, q*16 + 16);
        for (int p = q*16; p < pend; p++) {
            float w = flagv[p];
            float acc = hs;
            const float4* hv = (const float4*)hh[p];
            #pragma unroll
            for (int k = 0; k < 8; k++) {
                float4 v4 = hv[k];
                acc = fmaf(v4.x, w2c[4*k+0], acc);
                acc = fmaf(v4.y, w2c[4*k+1], acc);
                acc = fmaf(v4.z, w2c[4*k+2], acc);
                acc = fmaf(v4.w, w2c[4*k+3], acc);
            }
            if (w != 0.f) { s2 += acc; ss2 += acc*acc; mx2 = fmaxf(mx2, acc); mn2 = fminf(mn2, acc); }
        }
        __syncthreads();
    }

    red2[q][o] = s2; __syncthreads();
    if (q == 0) { float v = red2[0][o]+red2[1][o]+red2[2][o]+red2[3][o]; atomicAdd(base+O_SUM2+o, v); }
    __syncthreads();
    red2[q][o] = ss2; __syncthreads();
    if (q == 0) { float v = red2[0][o]+red2[1][o]+red2[2][o]+red2[3][o]; atomicAdd(base+O_SUMSQ2+o, v); }
    __syncthreads();
    red2[q][o] = mx2; __syncthreads();
    if (q == 0) { float v = fmaxf(fmaxf(red2[0][o], red2[1][o]), fmaxf(red2[2][o], red2[3][o]));
                  if (v > -FLT_MAX) atomicMaxF(base+O_SEGMAX2+b*64+o, v); }
    __syncthreads();
    red2[q][o] = mn2; __syncthreads();
    if (q == 0) { float v = fminf(fminf(red2[0][o], red2[1][o]), fminf(red2[2][o], red2[3][o]));
                  if (v < FLT_MAX) atomicMinF(base+O_SEGMIN2+b*64+o, v); }
}

// fuses BN2 coefficients + pmax extraction
__global__ void pmaxKernel(const float* __restrict__ g2, const float* __restrict__ bb2, float* ws) {
    int br = blockIdx.y; float* base = ws + (size_t)br * PER_BRANCH;
    int b = blockIdx.x, o = threadIdx.x;  // 64
    float tot = 0.f;
    for (int k = 0; k < 64; k++) tot += base[O_CNT + k];
    float n = fmaxf(tot, 1.f);
    float m = base[O_SUM2 + o] / n;
    float v = base[O_SUMSQ2 + o] / n - m*m;
    float a = g2[o] * rsqrtf(v + 0.001f);
    float bv = bb2[o] - m*a;
    float out = 0.f;
    if (base[O_CNT + b] > 0.f) {
        float pre = (a >= 0.f) ? base[O_SEGMAX2 + b*64 + o] : base[O_SEGMIN2 + b*64 + o];
        out = fmaxf(a*pre + bv, 0.f);
    }
    base[O_PMAX + b*64 + o] = out;
}

// d = relu(bn(p2@Wc^T)) - relu(bn(p1@Wc^T)), one block per output column j
__global__ void dKernel(const float* __restrict__ Wc, const float* __restrict__ gc,
                        const float* __restrict__ bc, float* ws) {
    int j = blockIdx.x, i = threadIdx.x;  // 64 lanes = 64 rows
    const float* p1 = ws + 0*PER_BRANCH + O_PMAX;
    const float* p2 = ws + 1*PER_BRANCH + O_PMAX;
    float t1 = 0.f, t2 = 0.f;
    for (int c = 0; c < 64; c++) {
        float wc = Wc[(size_t)j*64 + c];
        t1 = fmaf(p1[i*64 + c], wc, t1);
        t2 = fmaf(p2[i*64 + c], wc, t2);
    }
    float m1 = t1, m2 = t2;
    for (int off = 32; off; off >>= 1) { m1 += __shfl_xor(m1, off); m2 += __shfl_xor(m2, off); }
    m1 *= (1.f/64.f); m2 *= (1.f/64.f);
    float d1 = t1 - m1, d2 = t2 - m2;
    float v1 = d1*d1, v2 = d2*d2;
    for (int off = 32; off; off >>= 1) { v1 += __shfl_xor(v1, off); v2 += __shfl_xor(v2, off); }
    v1 *= (1.f/64.f); v2 *= (1.f/64.f);
    float z1 = fmaxf(d1 * rsqrtf(v1 + 0.001f) * gc[j] + bc[j], 0.f);
    float z2 = fmaxf(d2 * rsqrtf(v2 + 0.001f) * gc[j] + bc[j], 0.f);
    ws[O_D + (size_t)i*1024 + j] = z2 - z1;
}

// h = bn(relu(d @ Wm1 + bm1)), one block per output column c
__global__ __launch_bounds__(256) void hKernel(const float* __restrict__ Wm1, const float* __restrict__ bm1,
                                               const float* __restrict__ gm, const float* __restrict__ bm,
                                               float* ws) {
    int cidx = blockIdx.x;
    int t = threadIdx.x;
    int i = t & 63, q = t >> 6;
    const float* d = ws + O_D;
    float part = 0.f;
    for (int k = q*256; k < q*256 + 256; k++)
        part = fmaf(d[(size_t)i*1024 + k], Wm1[(size_t)k*64 + cidx], part);
    __shared__ float red[4][64];
    red[q][i] = part; __syncthreads();
    if (t < 64) {
        float u = red[0][i] + red[1][i] + red[2][i] + red[3][i] + bm1[cidx];
        u = fmaxf(u, 0.f);
        float m = u;
        for (int off = 32; off; off >>= 1) m += __shfl_xor(m, off);
        m *= (1.f/64.f);
        float du = u - m;
        float v = du*du;
        for (int off = 32; off; off >>= 1) v += __shfl_xor(v, off);
        v *= (1.f/64.f);
        ws[O_HMLP + (size_t)i*64 + cidx] = du * rsqrtf(v + 1e-5f) * gm[cidx] + bm[cidx];
    }
}

__global__ void outKernel(const float* __restrict__ Wm2, const float* __restrict__ bm2,
                          const float* __restrict__ ws, float* out) {
    __shared__ float lg[64][5];
    __shared__ float lse[64];
    int t = threadIdx.x;  // 320 threads
    {
        int i = t / 5, j = t % 5;
        const float* h = ws + O_HMLP;
        float acc = bm2[j];
        for (int k = 0; k < 64; k++) acc = fmaf(h[i*64 + k], Wm2[k*5 + j], acc);
        lg[i][j] = acc;
    }
    __syncthreads();
    if (t < 64) {
        float mx = lg[t][0];
        for (int j = 1; j < 5; j++) mx = fmaxf(mx, lg[t][j]);
        float s = 0.f;
        for (int j = 0; j < 5; j++) s += expf(lg[t][j] - mx);
        lse[t] = mx + logf(s);
    }
    __syncthreads();
    out[t] = lg[t/5][t%5] - lse[t/5];
}

extern "C" void kernel_launch(void* const* d_in, const int* in_sizes, int n_in,
                              void* d_out, int out_size, void* d_ws, size_t ws_size,
                              hipStream_t stream) {
    const float* x0  = (const float*)d_in[0];
    const float* x1  = (const float*)d_in[1];
    const int*   bt0 = (const int*)d_in[2];
    const int*   bt1 = (const int*)d_in[3];
    const float* W1  = (const float*)d_in[5];
    const float* g1  = (const float*)d_in[6];
    const float* bb1 = (const float*)d_in[7];
    const float* W2  = (const float*)d_in[8];
    const float* g2  = (const float*)d_in[9];
    const float* bb2 = (const float*)d_in[10];
    const float* Wc  = (const float*)d_in[11];
    const float* gc  = (const float*)d_in[12];
    const float* bc  = (const float*)d_in[13];
    const float* Wm1 = (const float*)d_in[14];
    const float* bm1 = (const float*)d_in[15];
    const float* gm  = (const float*)d_in[16];
    const float* bm  = (const float*)d_in[17];
    const float* Wm2 = (const float*)d_in[18];
    const float* bm2 = (const float*)d_in[19];
    float* ws  = (float*)d_ws;
    float* out = (float*)d_out;
    int N = in_sizes[0] / 6;

    initKernel <<<dim3(74, 2),     dim3(256), 0, stream>>>(ws);
    foldW1Kernel<<<dim3(1),        dim3(32),  0, stream>>>(W1, ws);
    pass1Kernel<<<dim3(64*S1, 2),  dim3(256), 0, stream>>>(x0, bt0, x1, bt1, N, ws);
    bias1Kernel<<<dim3(64, 2),     dim3(32),  0, stream>>>(W1, ws);
    pass2Kernel<<<dim3(64*S2, 2),  dim3(256), 0, stream>>>(x0, bt0, x1, bt1, N, ws);
    hsegKernel <<<dim3(64, 2),     dim3(64),  0, stream>>>(W2, g1, bb1, ws);
    pass3Kernel<<<dim3(64*S3, 2),  dim3(256), 0, stream>>>(x0, bt0, x1, bt1, N, W2, ws);
    pmaxKernel <<<dim3(64, 2),     dim3(64),  0, stream>>>(g2, bb2, ws);
    dKernel    <<<dim3(1024),      dim3(64),  0, stream>>>(Wc, gc, bc, ws);
    hKernel    <<<dim3(64),        dim3(256), 0, stream>>>(Wm1, bm1, gm, bm, ws);
    outKernel  <<<dim3(1),         dim3(320), 0, stream>>>(Wm2, bm2, ws, out);
}

// Round 2
// 245.745 us; speedup vs baseline: 1.0919x; 1.0919x over previous
//
#include <hip/hip_runtime.h>
#include <float.h>
#include <math.h>

// ---- workspace layout (floats) ----
#define PER_BRANCH 23040
#define O_CNT     0        // 64
#define O_PSUM    64       // 192
#define O_BIAS1   256      // 2048
#define O_RAWSUM  2304     // 2048
#define O_RAWSQ   4352     // 2048
#define O_RAWMAX  6400     // 2048
#define O_RAWMIN  8448     // 2048
#define O_AB1     10496    // 64 (a1[32], b1[32])
#define O_HSEG    10560    // 4096
#define O_SUM2    14656    // 64
#define O_SUMSQ2  14720    // 64
#define O_SEGMAX2 14784    // 4096
#define O_SEGMIN2 18880    // 4096
// shared region
#define O_U       (2*PER_BRANCH)   // 192
#define O_C32     (O_U+192)        // 32
#define O_PMAX    (O_C32+32)       // 8192 (both branches: br*4096)
#define O_D       (O_PMAX+8192)    // 65536
#define O_HMLP    (O_D+65536)      // 4096

#define SA 16
#define SB 16
#define T3 64

__device__ __forceinline__ int lower_bound_i(const int* a, int n, int v) {
    int lo = 0, hi = n;
    while (lo < hi) { int mid = (lo + hi) >> 1; if (a[mid] < v) lo = mid + 1; else hi = mid; }
    return lo;
}
__device__ __forceinline__ void atomicMaxF(float* a, float v) {
    if (v >= 0.f) atomicMax((int*)a, __float_as_int(v));
    else atomicMin((unsigned int*)a, (unsigned int)__float_as_int(v));
}
__device__ __forceinline__ void atomicMinF(float* a, float v) {
    if (v >= 0.f) atomicMin((int*)a, __float_as_int(v));
    else atomicMax((unsigned int*)a, (unsigned int)__float_as_int(v));
}
__device__ __forceinline__ bool is_valid(float p0, float p1) {
    return (floorf((p0 + 3.f) / 6.f) == 0.f) && (floorf((p1 + 3.f) / 6.f) == 0.f);
}

// init all atomically-accumulated regions; block (89, y=0) also folds W1 -> U, C32
__global__ void initKernel(const float* __restrict__ W1, float* ws) {
    int t = blockIdx.x * blockDim.x + threadIdx.x;
    float* base = ws + (size_t)blockIdx.y * PER_BRANCH;
    if (t < 256) base[t] = 0.f;
    else if (t >= O_RAWSUM  && t < O_RAWMAX)        base[t] = 0.f;
    else if (t >= O_RAWMAX  && t < O_RAWMIN)        base[t] = -FLT_MAX;
    else if (t >= O_RAWMIN  && t < O_AB1)           base[t] =  FLT_MAX;
    else if (t >= O_SUM2    && t < O_SEGMAX2)       base[t] = 0.f;
    else if (t >= O_SEGMAX2 && t < O_SEGMIN2)       base[t] = -FLT_MAX;
    else if (t >= O_SEGMIN2 && t < O_SEGMIN2+4096)  base[t] =  FLT_MAX;
    if (blockIdx.x == 89 && blockIdx.y == 0 && threadIdx.x < 32) {
        int c = threadIdx.x;
        float* U = ws + O_U;
        U[0*32+c] = W1[0*32+c] + W1[3*32+c] + W1[6*32+c];
        U[1*32+c] = W1[1*32+c] + W1[4*32+c] + W1[7*32+c];
        U[2*32+c] = W1[2*32+c] + W1[5*32+c] + W1[8*32+c];
        U[3*32+c] = W1[9*32+c];
        U[4*32+c] = W1[10*32+c];
        U[5*32+c] = W1[11*32+c];
        ws[O_C32+c] = 3.f * (W1[6*32+c] + W1[7*32+c]);
    }
}

// merged pass1+pass2: cnt, psum, and per-(segment,channel) raw-h sum/sumsq/max/min
__global__ __launch_bounds__(256) void passAKernel(const float* __restrict__ x0, const int* __restrict__ bt0,
                                                   const float* __restrict__ x1, const int* __restrict__ bt1,
                                                   int N, float* ws) {
    int br = blockIdx.y;
    const float* x = br ? x1 : x0;
    const int* batch = br ? bt1 : bt0;
    float* base = ws + (size_t)br * PER_BRANCH;
    int b = blockIdx.x / SA, s = blockIdx.x % SA;
    int lo = lower_bound_i(batch, N, b), hi = lower_bound_i(batch, N, b + 1);
    int chunk = (hi - lo + SA - 1) / SA;
    int beg = lo + s * chunk, end = min(hi, beg + chunk);

    __shared__ float Ul[6][32];
    int t = threadIdx.x;
    if (t < 192) Ul[t / 32][t & 31] = ws[O_U + t];
    __syncthreads();

    int c = t & 31, g = t >> 5;
    float u0=Ul[0][c], u1=Ul[1][c], u2=Ul[2][c], u3=Ul[3][c], u4=Ul[4][c], u5=Ul[5][c];
    float s1 = 0, ss = 0, mx = -FLT_MAX, mn = FLT_MAX;
    float cnt = 0, sx = 0, sy = 0, sz = 0;
    for (int i = beg + g; i < end; i += 8) {
        const float2* px = (const float2*)(x + (size_t)i * 6);
        float2 q0 = px[0], q1 = px[1], q2 = px[2];
        float p0=q0.x, p1=q0.y, p2=q1.x, e0=q1.y, e1=q2.x, e2=q2.y;
        if (is_valid(p0, p1)) {
            float h = fmaf(p0,u0, fmaf(p1,u1, fmaf(p2,u2, fmaf(e0,u3, fmaf(e1,u4, e2*u5)))));
            s1 += h; ss = fmaf(h, h, ss); mx = fmaxf(mx, h); mn = fminf(mn, h);
            if (c == 0) { cnt += 1.f; sx += p0; sy += p1; sz += p2; }
        }
    }
    __shared__ float red[8][32];
    red[g][c] = s1; __syncthreads();
    if (g == 0) { float v=0; for (int k=0;k<8;k++) v += red[k][c]; atomicAdd(base+O_RAWSUM+b*32+c, v); }
    __syncthreads();
    red[g][c] = ss; __syncthreads();
    if (g == 0) { float v=0; for (int k=0;k<8;k++) v += red[k][c]; atomicAdd(base+O_RAWSQ+b*32+c, v); }
    __syncthreads();
    red[g][c] = mx; __syncthreads();
    if (g == 0) { float v=-FLT_MAX; for (int k=0;k<8;k++) v = fmaxf(v, red[k][c]);
                  if (v > -FLT_MAX) atomicMaxF(base+O_RAWMAX+b*32+c, v); }
    __syncthreads();
    red[g][c] = mn; __syncthreads();
    if (g == 0) { float v=FLT_MAX; for (int k=0;k<8;k++) v = fminf(v, red[k][c]);
                  if (v < FLT_MAX) atomicMinF(base+O_RAWMIN+b*32+c, v); }
    __syncthreads();
    if (c == 0) { red[g][0]=cnt; red[g][1]=sx; red[g][2]=sy; red[g][3]=sz; }
    __syncthreads();
    if (t == 0) {
        float tc=0, tx=0, ty=0, tz=0;
        for (int w = 0; w < 8; w++) { tc+=red[w][0]; tx+=red[w][1]; ty+=red[w][2]; tz+=red[w][3]; }
        atomicAdd(base + O_CNT + b, tc);
        atomicAdd(base + O_PSUM + b*3 + 0, tx);
        atomicAdd(base + O_PSUM + b*3 + 1, ty);
        atomicAdd(base + O_PSUM + b*3 + 2, tz);
    }
}

// per-branch: bias_b[c] and BN1 coefficients from raw stats (analytic bias fold)
__global__ void bnCoefKernel(const float* __restrict__ W1, const float* __restrict__ g1,
                             const float* __restrict__ bb1, float* ws) {
    int br = blockIdx.y; float* base = ws + (size_t)br * PER_BRANCH;
    int t = threadIdx.x, c = t & 31, bg = t >> 5;   // 8 groups x 8 segments
    float ps1 = 0.f, pss = 0.f;
    for (int j = 0; j < 8; j++) {
        int b = bg * 8 + j;
        float cb = base[O_CNT + b];
        float cn = fmaxf(cb, 1.f);
        float mx = base[O_PSUM + b*3 + 0] / cn;
        float my = base[O_PSUM + b*3 + 1] / cn;
        float mz = base[O_PSUM + b*3 + 2] / cn;
        float bias = ws[O_C32 + c] - mx*W1[3*32+c] - my*W1[4*32+c] - mz*W1[5*32+c];
        base[O_BIAS1 + b*32 + c] = bias;
        float rs = base[O_RAWSUM + b*32 + c];
        float rq = base[O_RAWSQ  + b*32 + c];
        ps1 += rs + cb * bias;
        pss += rq + 2.f*bias*rs + cb*bias*bias;
    }
    __shared__ float red[8][32], red2[8][32];
    red[bg][c] = ps1; red2[bg][c] = pss; __syncthreads();
    if (bg == 0) {
        float s1 = 0.f, sq = 0.f;
        for (int k = 0; k < 8; k++) { s1 += red[k][c]; sq += red2[k][c]; }
        float tot = 0.f;
        for (int k = 0; k < 64; k++) tot += base[O_CNT + k];
        float n = fmaxf(tot, 1.f);
        float m = s1 / n;
        float v = sq / n - m*m;
        float a = g1[c] * rsqrtf(v + 0.001f);
        base[O_AB1 + c] = a;
        base[O_AB1 + 32 + c] = bb1[c] - m*a;
    }
}

// per-segment hmax (from raw max/min + bias) -> hseg = relu(bn1(hmax)) @ W2[32:]
__global__ void hsegKernel(const float* __restrict__ W2, float* ws) {
    int br = blockIdx.y; float* base = ws + (size_t)br * PER_BRANCH;
    int b = blockIdx.x, t = threadIdx.x;   // 64 threads
    __shared__ float hmaxv[32];
    if (t < 32) {
        float a = base[O_AB1 + t], bv = base[O_AB1 + 32 + t];
        float hm = 0.f;
        if (base[O_CNT + b] > 0.f) {
            float bias = base[O_BIAS1 + b*32 + t];
            float pre = (a >= 0.f) ? base[O_RAWMAX + b*32 + t] : base[O_RAWMIN + b*32 + t];
            hm = fmaxf(a*(pre + bias) + bv, 0.f);
        }
        hmaxv[t] = hm;
    }
    __syncthreads();
    float acc = 0.f;
    for (int k = 0; k < 32; k++) acc = fmaf(hmaxv[k], W2[(32 + k)*64 + t], acc);
    base[O_HSEG + b*64 + t] = acc;
}

__global__ __launch_bounds__(256) void passBKernel(const float* __restrict__ x0, const int* __restrict__ bt0,
                                                   const float* __restrict__ x1, const int* __restrict__ bt1,
                                                   int N, const float* __restrict__ W2, float* ws) {
    int br = blockIdx.y;
    const float* x = br ? x1 : x0;
    const int* batch = br ? bt1 : bt0;
    float* base = ws + (size_t)br * PER_BRANCH;
    int b = blockIdx.x / SB, s = blockIdx.x % SB;
    int lo = lower_bound_i(batch, N, b), hi = lower_bound_i(batch, N, b + 1);
    int chunk = (hi - lo + SB - 1) / SB;
    int beg = lo + s * chunk, end = min(hi, beg + chunk);

    __shared__ float Ul[6][32], b1l[32], a1l[32], bb1l[32], hsegl[64];
    __shared__ float hh[T3][32];
    __shared__ float flagv[T3];
    __shared__ float red2[4][64];
    int t = threadIdx.x;
    if (t < 192) Ul[t / 32][t & 31] = ws[O_U + t];
    if (t < 32) { b1l[t] = base[O_BIAS1 + b*32 + t]; a1l[t] = base[O_AB1 + t]; bb1l[t] = base[O_AB1 + 32 + t]; }
    if (t < 64) hsegl[t] = base[O_HSEG + b*64 + t];
    __syncthreads();

    int c = t & 31, g = t >> 5;   // stage1: 8 groups
    int o = t & 63, q = t >> 6;   // stage2: 4 groups
    float w2c[32];
    #pragma unroll
    for (int k = 0; k < 32; k++) w2c[k] = W2[k*64 + o];

    float u0=Ul[0][c], u1=Ul[1][c], u2=Ul[2][c], u3=Ul[3][c], u4=Ul[4][c], u5=Ul[5][c];
    float bb=b1l[c], a1=a1l[c], ab=bb1l[c], hs=hsegl[o];
    float s2 = 0, ss2 = 0, mx2 = -FLT_MAX, mn2 = FLT_MAX;

    for (int tile = beg; tile < end; tile += T3) {
        int npts = min(T3, end - tile);
        for (int p = g; p < npts; p += 8) {
            const float2* px = (const float2*)(x + (size_t)(tile + p) * 6);
            float2 q0 = px[0], q1 = px[1], q2 = px[2];
            float p0=q0.x, p1=q0.y, p2=q1.x, e0=q1.y, e1=q2.x, e2=q2.y;
            float h1 = fmaf(p0,u0, fmaf(p1,u1, fmaf(p2,u2, fmaf(e0,u3, fmaf(e1,u4, fmaf(e2,u5, bb))))));
            hh[p][c] = fmaxf(a1*h1 + ab, 0.f);
            if (c == 0) flagv[p] = is_valid(p0, p1) ? 1.f : 0.f;
        }
        __syncthreads();
        int pend = min(npts, q*16 + 16);
        for (int p = q*16; p < pend; p++) {
            float w = flagv[p];
            const float4* hv = (const float4*)hh[p];
            float acc[4] = {hs, 0.f, 0.f, 0.f};
            #pragma unroll
            for (int k = 0; k < 8; k++) {
                float4 v4 = hv[k];
                acc[0] = fmaf(v4.x, w2c[4*k+0], acc[0]);
                acc[1] = fmaf(v4.y, w2c[4*k+1], acc[1]);
                acc[2] = fmaf(v4.z, w2c[4*k+2], acc[2]);
                acc[3] = fmaf(v4.w, w2c[4*k+3], acc[3]);
            }
            float accf = (acc[0]+acc[1]) + (acc[2]+acc[3]);
            if (w != 0.f) { s2 += accf; ss2 = fmaf(accf, accf, ss2); mx2 = fmaxf(mx2, accf); mn2 = fminf(mn2, accf); }
        }
        __syncthreads();
    }

    red2[q][o] = s2; __syncthreads();
    if (q == 0) { float v = red2[0][o]+red2[1][o]+red2[2][o]+red2[3][o]; atomicAdd(base+O_SUM2+o, v); }
    __syncthreads();
    red2[q][o] = ss2; __syncthreads();
    if (q == 0) { float v = red2[0][o]+red2[1][o]+red2[2][o]+red2[3][o]; atomicAdd(base+O_SUMSQ2+o, v); }
    __syncthreads();
    red2[q][o] = mx2; __syncthreads();
    if (q == 0) { float v = fmaxf(fmaxf(red2[0][o], red2[1][o]), fmaxf(red2[2][o], red2[3][o]));
                  if (v > -FLT_MAX) atomicMaxF(base+O_SEGMAX2+b*64+o, v); }
    __syncthreads();
    red2[q][o] = mn2; __syncthreads();
    if (q == 0) { float v = fminf(fminf(red2[0][o], red2[1][o]), fminf(red2[2][o], red2[3][o]));
                  if (v < FLT_MAX) atomicMinF(base+O_SEGMIN2+b*64+o, v); }
}

// BN2 coefficients + pmax extraction
__global__ void pmaxKernel(const float* __restrict__ g2, const float* __restrict__ bb2, float* ws) {
    int br = blockIdx.y; float* base = ws + (size_t)br * PER_BRANCH;
    int b = blockIdx.x, o = threadIdx.x;  // 64
    float tot = 0.f;
    for (int k = 0; k < 64; k++) tot += base[O_CNT + k];
    float n = fmaxf(tot, 1.f);
    float m = base[O_SUM2 + o] / n;
    float v = base[O_SUMSQ2 + o] / n - m*m;
    float a = g2[o] * rsqrtf(v + 0.001f);
    float bv = bb2[o] - m*a;
    float out = 0.f;
    if (base[O_CNT + b] > 0.f) {
        float pre = (a >= 0.f) ? base[O_SEGMAX2 + b*64 + o] : base[O_SEGMIN2 + b*64 + o];
        out = fmaxf(a*pre + bv, 0.f);
    }
    ws[O_PMAX + (size_t)br*4096 + b*64 + o] = out;
}

// d = relu(bn(p2@Wc^T)) - relu(bn(p1@Wc^T)), one block per output column j
__global__ void dKernel(const float* __restrict__ Wc, const float* __restrict__ gc,
                        const float* __restrict__ bc, float* ws) {
    int j = blockIdx.x, i = threadIdx.x;  // 64 lanes = 64 rows
    const float* p1 = ws + O_PMAX;
    const float* p2 = ws + O_PMAX + 4096;
    float t1 = 0.f, t2 = 0.f;
    for (int c = 0; c < 64; c++) {
        float wc = Wc[(size_t)j*64 + c];
        t1 = fmaf(p1[i*64 + c], wc, t1);
        t2 = fmaf(p2[i*64 + c], wc, t2);
    }
    float m1 = t1, m2 = t2;
    for (int off = 32; off; off >>= 1) { m1 += __shfl_xor(m1, off); m2 += __shfl_xor(m2, off); }
    m1 *= (1.f/64.f); m2 *= (1.f/64.f);
    float d1 = t1 - m1, d2 = t2 - m2;
    float v1 = d1*d1, v2 = d2*d2;
    for (int off = 32; off; off >>= 1) { v1 += __shfl_xor(v1, off); v2 += __shfl_xor(v2, off); }
    v1 *= (1.f/64.f); v2 *= (1.f/64.f);
    float z1 = fmaxf(d1 * rsqrtf(v1 + 0.001f) * gc[j] + bc[j], 0.f);
    float z2 = fmaxf(d2 * rsqrtf(v2 + 0.001f) * gc[j] + bc[j], 0.f);
    ws[O_D + (size_t)i*1024 + j] = z2 - z1;
}

// h = bn(relu(d @ Wm1 + bm1)), one block per output column c
__global__ __launch_bounds__(256) void hKernel(const float* __restrict__ Wm1, const float* __restrict__ bm1,
                                               const float* __restrict__ gm, const float* __restrict__ bm,
                                               float* ws) {
    int cidx = blockIdx.x;
    int t = threadIdx.x;
    int i = t & 63, q = t >> 6;
    const float* d = ws + O_D;
    float part = 0.f;
    for (int k = q*256; k < q*256 + 256; k++)
        part = fmaf(d[(size_t)i*1024 + k], Wm1[(size_t)k*64 + cidx], part);
    __shared__ float red[4][64];
    red[q][i] = part; __syncthreads();
    if (t < 64) {
        float u = red[0][i] + red[1][i] + red[2][i] + red[3][i] + bm1[cidx];
        u = fmaxf(u, 0.f);
        float m = u;
        for (int off = 32; off; off >>= 1) m += __shfl_xor(m, off);
        m *= (1.f/64.f);
        float du = u - m;
        float v = du*du;
        for (int off = 32; off; off >>= 1) v += __shfl_xor(v, off);
        v *= (1.f/64.f);
        ws[O_HMLP + (size_t)i*64 + cidx] = du * rsqrtf(v + 1e-5f) * gm[cidx] + bm[cidx];
    }
}

__global__ void outKernel(const float* __restrict__ Wm2, const float* __restrict__ bm2,
                          const float* __restrict__ ws, float* out) {
    __shared__ float lg[64][5];
    __shared__ float lse[64];
    int t = threadIdx.x;  // 320 threads
    {
        int i = t / 5, j = t % 5;
        const float* h = ws + O_HMLP;
        float acc = bm2[j];
        for (int k = 0; k < 64; k++) acc = fmaf(h[i*64 + k], Wm2[k*5 + j], acc);
        lg[i][j] = acc;
    }
    __syncthreads();
    if (t < 64) {
        float mx = lg[t][0];
        for (int j = 1; j < 5; j++) mx = fmaxf(mx, lg[t][j]);
        float s = 0.f;
        for (int j = 0; j < 5; j++) s += expf(lg[t][j] - mx);
        lse[t] = mx + logf(s);
    }
    __syncthreads();
    out[t] = lg[t/5][t%5] - lse[t/5];
}

extern "C" void kernel_launch(void* const* d_in, const int* in_sizes, int n_in,
                              void* d_out, int out_size, void* d_ws, size_t ws_size,
                              hipStream_t stream) {
    const float* x0  = (const float*)d_in[0];
    const float* x1  = (const float*)d_in[1];
    const int*   bt0 = (const int*)d_in[2];
    const int*   bt1 = (const int*)d_in[3];
    const float* W1  = (const float*)d_in[5];
    const float* g1  = (const float*)d_in[6];
    const float* bb1 = (const float*)d_in[7];
    const float* W2  = (const float*)d_in[8];
    const float* g2  = (const float*)d_in[9];
    const float* bb2 = (const float*)d_in[10];
    const float* Wc  = (const float*)d_in[11];
    const float* gc  = (const float*)d_in[12];
    const float* bc  = (const float*)d_in[13];
    const float* Wm1 = (const float*)d_in[14];
    const float* bm1 = (const float*)d_in[15];
    const float* gm  = (const float*)d_in[16];
    const float* bm  = (const float*)d_in[17];
    const float* Wm2 = (const float*)d_in[18];
    const float* bm2 = (const float*)d_in[19];
    float* ws  = (float*)d_ws;
    float* out = (float*)d_out;
    int N = in_sizes[0] / 6;

    initKernel  <<<dim3(90, 2),     dim3(256), 0, stream>>>(W1, ws);
    passAKernel <<<dim3(64*SA, 2),  dim3(256), 0, stream>>>(x0, bt0, x1, bt1, N, ws);
    bnCoefKernel<<<dim3(1, 2),      dim3(256), 0, stream>>>(W1, g1, bb1, ws);
    hsegKernel  <<<dim3(64, 2),     dim3(64),  0, stream>>>(W2, ws);
    passBKernel <<<dim3(64*SB, 2),  dim3(256), 0, stream>>>(x0, bt0, x1, bt1, N, W2, ws);
    pmaxKernel  <<<dim3(64, 2),     dim3(64),  0, stream>>>(g2, bb2, ws);
    dKernel     <<<dim3(1024),      dim3(64),  0, stream>>>(Wc, gc, bc, ws);
    hKernel     <<<dim3(64),        dim3(256), 0, stream>>>(Wm1, bm1, gm, bm, ws);
    outKernel   <<<dim3(1),         dim3(320), 0, stream>>>(Wm2, bm2, ws, out);
}

// Round 3
// 170.430 us; speedup vs baseline: 1.5745x; 1.4419x over previous
//
#include <hip/hip_runtime.h>
#include <float.h>
#include <math.h>

// ---- workspace layout (floats) ----
#define PER_BRANCH 32768
#define O_CNT     0        // 64
#define O_PSUM    64       // 192
#define O_BIAS1   256      // 2048
#define O_RAWSUM  2304     // 2048
#define O_RAWSQ   4352     // 2048
#define O_RAWMAX  6400     // 2048
#define O_RAWMIN  8448     // 2048
#define O_AB1     10496    // 64 (a1[32], b1[32])
#define O_HSEG    10560    // 4096
#define O_SEGSUM2 14656    // 4096 (raw per-seg sum of mm)
#define O_SEGSQ2  18752    // 4096
#define O_SEGMAX2 22848    // 4096 (raw)
#define O_SEGMIN2 26944    // 4096 (raw)
#define O_AB2     31040    // 128
// shared region
#define O_U       (2*PER_BRANCH)   // 192
#define O_C32     (O_U+192)        // 32
#define O_W2BF    (O_C32+32)       // 1024 floats = 2048 bf16 (W2[:32] rows, k-major)
#define O_PMAX    (O_W2BF+1024)    // 8192 (br*4096)
#define O_D       (O_PMAX+8192)    // 65536
#define O_HMLP    (O_D+65536)      // 4096

#define SA 16
#define SB 16

typedef __attribute__((ext_vector_type(8))) short short8;
typedef __attribute__((ext_vector_type(4))) float f32x4;

__device__ __forceinline__ int lower_bound_i(const int* a, int n, int v) {
    int lo = 0, hi = n;
    while (lo < hi) { int mid = (lo + hi) >> 1; if (a[mid] < v) lo = mid + 1; else hi = mid; }
    return lo;
}
__device__ __forceinline__ void atomicMaxF(float* a, float v) {
    if (v >= 0.f) atomicMax((int*)a, __float_as_int(v));
    else atomicMin((unsigned int*)a, (unsigned int)__float_as_int(v));
}
__device__ __forceinline__ void atomicMinF(float* a, float v) {
    if (v >= 0.f) atomicMin((int*)a, __float_as_int(v));
    else atomicMax((unsigned int*)a, (unsigned int)__float_as_int(v));
}
__device__ __forceinline__ bool is_valid(float p0, float p1) {
    return (floorf((p0 + 3.f) / 6.f) == 0.f) && (floorf((p1 + 3.f) / 6.f) == 0.f);
}
__device__ __forceinline__ unsigned short f2bf(float x) {
    unsigned int u = __float_as_uint(x);
    return (unsigned short)((u + 0x7FFFu + ((u >> 16) & 1u)) >> 16);   // RNE
}

// init accumulated regions; branch-0 also converts W2[:32] to bf16 and folds W1
__global__ void initKernel(const float* __restrict__ W1, const float* __restrict__ W2, float* ws) {
    int t = blockIdx.x * blockDim.x + threadIdx.x;
    float* base = ws + (size_t)blockIdx.y * PER_BRANCH;
    if (t < 256) base[t] = 0.f;
    else if (t >= O_RAWSUM  && t < O_RAWMAX)         base[t] = 0.f;
    else if (t >= O_RAWMAX  && t < O_RAWMIN)         base[t] = -FLT_MAX;
    else if (t >= O_RAWMIN  && t < O_AB1)            base[t] =  FLT_MAX;
    else if (t >= O_SEGSUM2 && t < O_SEGMAX2)        base[t] = 0.f;
    else if (t >= O_SEGMAX2 && t < O_SEGMIN2)        base[t] = -FLT_MAX;
    else if (t >= O_SEGMIN2 && t < O_SEGMIN2+4096)   base[t] =  FLT_MAX;
    if (blockIdx.y == 0) {
        if (t < 1024) {   // W2 rows 0..31 -> bf16, same [k][n] layout
            unsigned int lo = f2bf(W2[2*t]);
            unsigned int hi = f2bf(W2[2*t+1]);
            ((unsigned int*)(ws + O_W2BF))[t] = lo | (hi << 16);
        }
        if (blockIdx.x == 0 && threadIdx.x < 32) {
            int c = threadIdx.x;
            float* U = ws + O_U;
            U[0*32+c] = W1[0*32+c] + W1[3*32+c] + W1[6*32+c];
            U[1*32+c] = W1[1*32+c] + W1[4*32+c] + W1[7*32+c];
            U[2*32+c] = W1[2*32+c] + W1[5*32+c] + W1[8*32+c];
            U[3*32+c] = W1[9*32+c];
            U[4*32+c] = W1[10*32+c];
            U[5*32+c] = W1[11*32+c];
            ws[O_C32+c] = 3.f * (W1[6*32+c] + W1[7*32+c]);
        }
    }
}

// pass A: cnt, psum, per-(segment,channel) raw-h1 sum/sumsq/max/min (fp32, unchanged)
__global__ __launch_bounds__(256) void passAKernel(const float* __restrict__ x0, const int* __restrict__ bt0,
                                                   const float* __restrict__ x1, const int* __restrict__ bt1,
                                                   int N, float* ws) {
    int br = blockIdx.y;
    const float* x = br ? x1 : x0;
    const int* batch = br ? bt1 : bt0;
    float* base = ws + (size_t)br * PER_BRANCH;
    int b = blockIdx.x / SA, s = blockIdx.x % SA;
    int lo = lower_bound_i(batch, N, b), hi = lower_bound_i(batch, N, b + 1);
    int chunk = (hi - lo + SA - 1) / SA;
    int beg = lo + s * chunk, end = min(hi, beg + chunk);

    __shared__ float Ul[6][32];
    int t = threadIdx.x;
    if (t < 192) Ul[t / 32][t & 31] = ws[O_U + t];
    __syncthreads();

    int c = t & 31, g = t >> 5;
    float u0=Ul[0][c], u1=Ul[1][c], u2=Ul[2][c], u3=Ul[3][c], u4=Ul[4][c], u5=Ul[5][c];
    float s1 = 0, ss = 0, mx = -FLT_MAX, mn = FLT_MAX;
    float cnt = 0, sx = 0, sy = 0, sz = 0;
    for (int i = beg + g; i < end; i += 8) {
        const float2* px = (const float2*)(x + (size_t)i * 6);
        float2 q0 = px[0], q1 = px[1], q2 = px[2];
        float p0=q0.x, p1=q0.y, p2=q1.x, e0=q1.y, e1=q2.x, e2=q2.y;
        if (is_valid(p0, p1)) {
            float h = fmaf(p0,u0, fmaf(p1,u1, fmaf(p2,u2, fmaf(e0,u3, fmaf(e1,u4, e2*u5)))));
            s1 += h; ss = fmaf(h, h, ss); mx = fmaxf(mx, h); mn = fminf(mn, h);
            if (c == 0) { cnt += 1.f; sx += p0; sy += p1; sz += p2; }
        }
    }
    __shared__ float red[8][32];
    red[g][c] = s1; __syncthreads();
    if (g == 0) { float v=0; for (int k=0;k<8;k++) v += red[k][c]; atomicAdd(base+O_RAWSUM+b*32+c, v); }
    __syncthreads();
    red[g][c] = ss; __syncthreads();
    if (g == 0) { float v=0; for (int k=0;k<8;k++) v += red[k][c]; atomicAdd(base+O_RAWSQ+b*32+c, v); }
    __syncthreads();
    red[g][c] = mx; __syncthreads();
    if (g == 0) { float v=-FLT_MAX; for (int k=0;k<8;k++) v = fmaxf(v, red[k][c]);
                  if (v > -FLT_MAX) atomicMaxF(base+O_RAWMAX+b*32+c, v); }
    __syncthreads();
    red[g][c] = mn; __syncthreads();
    if (g == 0) { float v=FLT_MAX; for (int k=0;k<8;k++) v = fminf(v, red[k][c]);
                  if (v < FLT_MAX) atomicMinF(base+O_RAWMIN+b*32+c, v); }
    __syncthreads();
    if (c == 0) { red[g][0]=cnt; red[g][1]=sx; red[g][2]=sy; red[g][3]=sz; }
    __syncthreads();
    if (t == 0) {
        float tc=0, tx=0, ty=0, tz=0;
        for (int w = 0; w < 8; w++) { tc+=red[w][0]; tx+=red[w][1]; ty+=red[w][2]; tz+=red[w][3]; }
        atomicAdd(base + O_CNT + b, tc);
        atomicAdd(base + O_PSUM + b*3 + 0, tx);
        atomicAdd(base + O_PSUM + b*3 + 1, ty);
        atomicAdd(base + O_PSUM + b*3 + 2, tz);
    }
}

// bias_b[c] and BN1 coefficients from raw stats (analytic bias fold)
__global__ void bnCoefKernel(const float* __restrict__ W1, const float* __restrict__ g1,
                             const float* __restrict__ bb1, float* ws) {
    int br = blockIdx.y; float* base = ws + (size_t)br * PER_BRANCH;
    int t = threadIdx.x, c = t & 31, bg = t >> 5;
    float ps1 = 0.f, pss = 0.f;
    for (int j = 0; j < 8; j++) {
        int b = bg * 8 + j;
        float cb = base[O_CNT + b];
        float cn = fmaxf(cb, 1.f);
        float mx = base[O_PSUM + b*3 + 0] / cn;
        float my = base[O_PSUM + b*3 + 1] / cn;
        float mz = base[O_PSUM + b*3 + 2] / cn;
        float bias = ws[O_C32 + c] - mx*W1[3*32+c] - my*W1[4*32+c] - mz*W1[5*32+c];
        base[O_BIAS1 + b*32 + c] = bias;
        float rs = base[O_RAWSUM + b*32 + c];
        float rq = base[O_RAWSQ  + b*32 + c];
        ps1 += rs + cb * bias;
        pss += rq + 2.f*bias*rs + cb*bias*bias;
    }
    __shared__ float red[8][32], red2[8][32];
    red[bg][c] = ps1; red2[bg][c] = pss; __syncthreads();
    if (bg == 0) {
        float s1 = 0.f, sq = 0.f;
        for (int k = 0; k < 8; k++) { s1 += red[k][c]; sq += red2[k][c]; }
        float tot = 0.f;
        for (int k = 0; k < 64; k++) tot += base[O_CNT + k];
        float n = fmaxf(tot, 1.f);
        float m = s1 / n;
        float v = sq / n - m*m;
        float a = g1[c] * rsqrtf(v + 0.001f);
        base[O_AB1 + c] = a;
        base[O_AB1 + 32 + c] = bb1[c] - m*a;
    }
}

// per-segment hmax -> hseg = relu(bn1(hmax)) @ W2[32:]  (fp32)
__global__ void hsegKernel(const float* __restrict__ W2, float* ws) {
    int br = blockIdx.y; float* base = ws + (size_t)br * PER_BRANCH;
    int b = blockIdx.x, t = threadIdx.x;   // 64 threads
    __shared__ float hmaxv[32];
    if (t < 32) {
        float a = base[O_AB1 + t], bv = base[O_AB1 + 32 + t];
        float hm = 0.f;
        if (base[O_CNT + b] > 0.f) {
            float bias = base[O_BIAS1 + b*32 + t];
            float pre = (a >= 0.f) ? base[O_RAWMAX + b*32 + t] : base[O_RAWMIN + b*32 + t];
            hm = fmaxf(a*(pre + bias) + bv, 0.f);
        }
        hmaxv[t] = hm;
    }
    __syncthreads();
    float acc = 0.f;
    for (int k = 0; k < 32; k++) acc = fmaf(hmaxv[k], W2[(32 + k)*64 + t], acc);
    base[O_HSEG + b*64 + t] = acc;
}

// pass B: MFMA. mm = relu(bn1(h1)) @ W2[:32] per point; per-seg raw stats of mm.
__global__ __launch_bounds__(256) void passBKernel(const float* __restrict__ x0, const int* __restrict__ bt0,
                                                   const float* __restrict__ x1, const int* __restrict__ bt1,
                                                   int N, float* ws) {
    int br = blockIdx.y;
    const float* x = br ? x1 : x0;
    const int* batch = br ? bt1 : bt0;
    float* base = ws + (size_t)br * PER_BRANCH;
    int b = blockIdx.x / SB, s = blockIdx.x % SB;
    int lo = lower_bound_i(batch, N, b), hi = lower_bound_i(batch, N, b + 1);
    int chunk = (hi - lo + SB - 1) / SB;
    int beg = lo + s * chunk, end = min(hi, beg + chunk);

    __shared__ unsigned short A_lds[64 * 40];   // bf16 [64 pts][32 ch + 8 pad] (80B rows)
    __shared__ float flagF[64];
    __shared__ float redX[4][64];

    int t = threadIdx.x;
    int l = t & 63, w = t >> 6;
    int g4 = l >> 4, n0 = l & 15;

    // ---- B fragments (held in regs for whole block) ----
    const unsigned short* w2u = (const unsigned short*)(ws + O_W2BF);
    short8 bfrag[4];
    #pragma unroll
    for (int ct = 0; ct < 4; ct++)
        #pragma unroll
        for (int j = 0; j < 8; j++)
            bfrag[ct][j] = (short)w2u[(8*g4 + j)*64 + 16*ct + n0];

    // ---- stage1 constants (2 channels per thread) ----
    int c2 = (t & 15) * 2, g16 = t >> 4;
    float uA[6], uB[6];
    #pragma unroll
    for (int k = 0; k < 6; k++) { uA[k] = ws[O_U + k*32 + c2]; uB[k] = ws[O_U + k*32 + c2 + 1]; }
    float biasA = base[O_BIAS1 + b*32 + c2],  biasB = base[O_BIAS1 + b*32 + c2 + 1];
    float a1A = base[O_AB1 + c2],  abA = base[O_AB1 + 32 + c2];
    float a1B = base[O_AB1 + c2+1], abB = base[O_AB1 + 32 + c2 + 1];

    f32x4 sAcc[4], qAcc[4], mxA[4], mnA[4];
    #pragma unroll
    for (int ct = 0; ct < 4; ct++) {
        sAcc[ct] = (f32x4){0,0,0,0}; qAcc[ct] = (f32x4){0,0,0,0};
        mxA[ct] = (f32x4){-FLT_MAX,-FLT_MAX,-FLT_MAX,-FLT_MAX};
        mnA[ct] = (f32x4){ FLT_MAX, FLT_MAX, FLT_MAX, FLT_MAX};
    }

    for (int tile = beg; tile < end; tile += 64) {
        // stage1: h1 -> relu(bn1) -> bf16 into A_lds
        #pragma unroll
        for (int pp = 0; pp < 4; pp++) {
            int p = g16 + pp*16;
            int idx = tile + p;
            float ra = 0.f, rb = 0.f, flag = 0.f;
            if (idx < end) {
                const float2* px = (const float2*)(x + (size_t)idx * 6);
                float2 q0 = px[0], q1 = px[1], q2 = px[2];
                float p0=q0.x, p1=q0.y, p2=q1.x, e0=q1.y, e1=q2.x, e2=q2.y;
                float hA = fmaf(p0,uA[0], fmaf(p1,uA[1], fmaf(p2,uA[2], fmaf(e0,uA[3], fmaf(e1,uA[4], fmaf(e2,uA[5], biasA))))));
                float hB = fmaf(p0,uB[0], fmaf(p1,uB[1], fmaf(p2,uB[2], fmaf(e0,uB[3], fmaf(e1,uB[4], fmaf(e2,uB[5], biasB))))));
                ra = fmaxf(fmaf(a1A, hA, abA), 0.f);
                rb = fmaxf(fmaf(a1B, hB, abB), 0.f);
                flag = is_valid(p0, p1) ? 1.f : 0.f;
            }
            unsigned int pk = (unsigned int)f2bf(ra) | ((unsigned int)f2bf(rb) << 16);
            *(unsigned int*)&A_lds[p*40 + c2] = pk;
            if (c2 == 0) flagF[p] = flag;
        }
        __syncthreads();

        // stage2: MFMA + masked raw stats
        short8 af = *(const short8*)&A_lds[(16*w + n0)*40 + g4*8];
        f32x4 fl4 = *(const f32x4*)&flagF[16*w + 4*g4];
        #pragma unroll
        for (int ct = 0; ct < 4; ct++) {
            f32x4 cz = (f32x4){0,0,0,0};
            f32x4 v = __builtin_amdgcn_mfma_f32_16x16x32_bf16(af, bfrag[ct], cz, 0, 0, 0);
            #pragma unroll
            for (int r = 0; r < 4; r++) {
                float f = fl4[r];
                float vv = f * v[r];
                sAcc[ct][r] += vv;
                qAcc[ct][r] = fmaf(vv, v[r], qAcc[ct][r]);
                mxA[ct][r] = fmaxf(mxA[ct][r], (f != 0.f) ? v[r] : -FLT_MAX);
                mnA[ct][r] = fminf(mnA[ct][r], (f != 0.f) ? v[r] :  FLT_MAX);
            }
        }
        __syncthreads();
    }

    // ---- block epilogue: reduce rows then waves, atomics per (b, col) ----
    float sC[4], qC[4], mxC[4], mnC[4];
    #pragma unroll
    for (int ct = 0; ct < 4; ct++) {
        float sv = sAcc[ct][0]+sAcc[ct][1]+sAcc[ct][2]+sAcc[ct][3];
        float qv = qAcc[ct][0]+qAcc[ct][1]+qAcc[ct][2]+qAcc[ct][3];
        float mv = fmaxf(fmaxf(mxA[ct][0],mxA[ct][1]), fmaxf(mxA[ct][2],mxA[ct][3]));
        float nv = fminf(fminf(mnA[ct][0],mnA[ct][1]), fminf(mnA[ct][2],mnA[ct][3]));
        sv += __shfl_xor(sv, 16); sv += __shfl_xor(sv, 32);
        qv += __shfl_xor(qv, 16); qv += __shfl_xor(qv, 32);
        mv = fmaxf(mv, __shfl_xor(mv, 16)); mv = fmaxf(mv, __shfl_xor(mv, 32));
        nv = fminf(nv, __shfl_xor(nv, 16)); nv = fminf(nv, __shfl_xor(nv, 32));
        sC[ct]=sv; qC[ct]=qv; mxC[ct]=mv; mnC[ct]=nv;
    }
    // cross-wave via LDS, 4 stats sequentially
    if (l < 16) { for (int ct = 0; ct < 4; ct++) redX[w][16*ct + l] = sC[ct]; }
    __syncthreads();
    if (w == 0) { float v = redX[0][l]+redX[1][l]+redX[2][l]+redX[3][l]; atomicAdd(base+O_SEGSUM2+b*64+l, v); }
    __syncthreads();
    if (l < 16) { for (int ct = 0; ct < 4; ct++) redX[w][16*ct + l] = qC[ct]; }
    __syncthreads();
    if (w == 0) { float v = redX[0][l]+redX[1][l]+redX[2][l]+redX[3][l]; atomicAdd(base+O_SEGSQ2+b*64+l, v); }
    __syncthreads();
    if (l < 16) { for (int ct = 0; ct < 4; ct++) redX[w][16*ct + l] = mxC[ct]; }
    __syncthreads();
    if (w == 0) { float v = fmaxf(fmaxf(redX[0][l],redX[1][l]), fmaxf(redX[2][l],redX[3][l]));
                  if (v > -FLT_MAX) atomicMaxF(base+O_SEGMAX2+b*64+l, v); }
    __syncthreads();
    if (l < 16) { for (int ct = 0; ct < 4; ct++) redX[w][16*ct + l] = mnC[ct]; }
    __syncthreads();
    if (w == 0) { float v = fminf(fminf(redX[0][l],redX[1][l]), fminf(redX[2][l],redX[3][l]));
                  if (v < FLT_MAX) atomicMinF(base+O_SEGMIN2+b*64+l, v); }
}

// BN2 coefficients: fold per-seg hseg into global sums
__global__ void bn2Kernel(const float* __restrict__ g2, const float* __restrict__ bb2, float* ws) {
    int br = blockIdx.y; float* base = ws + (size_t)br * PER_BRANCH;
    int o = threadIdx.x;   // 64
    float S = 0.f, Q = 0.f, tot = 0.f;
    for (int b = 0; b < 64; b++) {
        float cb = base[O_CNT + b];
        float hs = base[O_HSEG + b*64 + o];
        float sb = base[O_SEGSUM2 + b*64 + o];
        float qb = base[O_SEGSQ2  + b*64 + o];
        S += sb + cb*hs;
        Q += qb + 2.f*hs*sb + cb*hs*hs;
        tot += cb;
    }
    float n = fmaxf(tot, 1.f);
    float m = S / n;
    float v = Q / n - m*m;
    float a = g2[o] * rsqrtf(v + 0.001f);
    base[O_AB2 + o] = a;
    base[O_AB2 + 64 + o] = bb2[o] - m*a;
}

// pmax extraction (raw max/min + hseg fold)
__global__ void pmaxKernel(float* ws) {
    int br = blockIdx.y; float* base = ws + (size_t)br * PER_BRANCH;
    int b = blockIdx.x, o = threadIdx.x;  // 64
    float a = base[O_AB2 + o], bv = base[O_AB2 + 64 + o];
    float out = 0.f;
    if (base[O_CNT + b] > 0.f) {
        float hs = base[O_HSEG + b*64 + o];
        float pre = ((a >= 0.f) ? base[O_SEGMAX2 + b*64 + o] : base[O_SEGMIN2 + b*64 + o]) + hs;
        out = fmaxf(fmaf(a, pre, bv), 0.f);
    }
    ws[O_PMAX + (size_t)br*4096 + b*64 + o] = out;
}

// d = relu(bn(p2@Wc^T)) - relu(bn(p1@Wc^T)), one block per output column j
__global__ void dKernel(const float* __restrict__ Wc, const float* __restrict__ gc,
                        const float* __restrict__ bc, float* ws) {
    int j = blockIdx.x, i = threadIdx.x;  // 64 lanes = 64 rows
    const float* p1 = ws + O_PMAX;
    const float* p2 = ws + O_PMAX + 4096;
    float t1 = 0.f, t2 = 0.f;
    for (int c = 0; c < 64; c++) {
        float wc = Wc[(size_t)j*64 + c];
        t1 = fmaf(p1[i*64 + c], wc, t1);
        t2 = fmaf(p2[i*64 + c], wc, t2);
    }
    float m1 = t1, m2 = t2;
    for (int off = 32; off; off >>= 1) { m1 += __shfl_xor(m1, off); m2 += __shfl_xor(m2, off); }
    m1 *= (1.f/64.f); m2 *= (1.f/64.f);
    float d1 = t1 - m1, d2 = t2 - m2;
    float v1 = d1*d1, v2 = d2*d2;
    for (int off = 32; off; off >>= 1) { v1 += __shfl_xor(v1, off); v2 += __shfl_xor(v2, off); }
    v1 *= (1.f/64.f); v2 *= (1.f/64.f);
    float z1 = fmaxf(d1 * rsqrtf(v1 + 0.001f) * gc[j] + bc[j], 0.f);
    float z2 = fmaxf(d2 * rsqrtf(v2 + 0.001f) * gc[j] + bc[j], 0.f);
    ws[O_D + (size_t)i*1024 + j] = z2 - z1;
}

// h = bn(relu(d @ Wm1 + bm1)), one block per output column c
__global__ __launch_bounds__(256) void hKernel(const float* __restrict__ Wm1, const float* __restrict__ bm1,
                                               const float* __restrict__ gm, const float* __restrict__ bm,
                                               float* ws) {
    int cidx = blockIdx.x;
    int t = threadIdx.x;
    int i = t & 63, q = t >> 6;
    const float* d = ws + O_D;
    float part = 0.f;
    for (int k = q*256; k < q*256 + 256; k++)
        part = fmaf(d[(size_t)i*1024 + k], Wm1[(size_t)k*64 + cidx], part);
    __shared__ float red[4][64];
    red[q][i] = part; __syncthreads();
    if (t < 64) {
        float u = red[0][i] + red[1][i] + red[2][i] + red[3][i] + bm1[cidx];
        u = fmaxf(u, 0.f);
        float m = u;
        for (int off = 32; off; off >>= 1) m += __shfl_xor(m, off);
        m *= (1.f/64.f);
        float du = u - m;
        float v = du*du;
        for (int off = 32; off; off >>= 1) v += __shfl_xor(v, off);
        v *= (1.f/64.f);
        ws[O_HMLP + (size_t)i*64 + cidx] = du * rsqrtf(v + 1e-5f) * gm[cidx] + bm[cidx];
    }
}

__global__ void outKernel(const float* __restrict__ Wm2, const float* __restrict__ bm2,
                          const float* __restrict__ ws, float* out) {
    __shared__ float lg[64][5];
    __shared__ float lse[64];
    int t = threadIdx.x;  // 320 threads
    {
        int i = t / 5, j = t % 5;
        const float* h = ws + O_HMLP;
        float acc = bm2[j];
        for (int k = 0; k < 64; k++) acc = fmaf(h[i*64 + k], Wm2[k*5 + j], acc);
        lg[i][j] = acc;
    }
    __syncthreads();
    if (t < 64) {
        float mx = lg[t][0];
        for (int j = 1; j < 5; j++) mx = fmaxf(mx, lg[t][j]);
        float s = 0.f;
        for (int j = 0; j < 5; j++) s += expf(lg[t][j] - mx);
        lse[t] = mx + logf(s);
    }
    __syncthreads();
    out[t] = lg[t/5][t%5] - lse[t/5];
}

extern "C" void kernel_launch(void* const* d_in, const int* in_sizes, int n_in,
                              void* d_out, int out_size, void* d_ws, size_t ws_size,
                              hipStream_t stream) {
    const float* x0  = (const float*)d_in[0];
    const float* x1  = (const float*)d_in[1];
    const int*   bt0 = (const int*)d_in[2];
    const int*   bt1 = (const int*)d_in[3];
    const float* W1  = (const float*)d_in[5];
    const float* g1  = (const float*)d_in[6];
    const float* bb1 = (const float*)d_in[7];
    const float* W2  = (const float*)d_in[8];
    const float* g2  = (const float*)d_in[9];
    const float* bb2 = (const float*)d_in[10];
    const float* Wc  = (const float*)d_in[11];
    const float* gc  = (const float*)d_in[12];
    const float* bc  = (const float*)d_in[13];
    const float* Wm1 = (const float*)d_in[14];
    const float* bm1 = (const float*)d_in[15];
    const float* gm  = (const float*)d_in[16];
    const float* bm  = (const float*)d_in[17];
    const float* Wm2 = (const float*)d_in[18];
    const float* bm2 = (const float*)d_in[19];
    float* ws  = (float*)d_ws;
    float* out = (float*)d_out;
    int N = in_sizes[0] / 6;

    initKernel  <<<dim3(122, 2),    dim3(256), 0, stream>>>(W1, W2, ws);
    passAKernel <<<dim3(64*SA, 2),  dim3(256), 0, stream>>>(x0, bt0, x1, bt1, N, ws);
    bnCoefKernel<<<dim3(1, 2),      dim3(256), 0, stream>>>(W1, g1, bb1, ws);
    hsegKernel  <<<dim3(64, 2),     dim3(64),  0, stream>>>(W2, ws);
    passBKernel <<<dim3(64*SB, 2),  dim3(256), 0, stream>>>(x0, bt0, x1, bt1, N, ws);
    bn2Kernel   <<<dim3(1, 2),      dim3(64),  0, stream>>>(g2, bb2, ws);
    pmaxKernel  <<<dim3(64, 2),     dim3(64),  0, stream>>>(ws);
    dKernel     <<<dim3(1024),      dim3(64),  0, stream>>>(Wc, gc, bc, ws);
    hKernel     <<<dim3(64),        dim3(256), 0, stream>>>(Wm1, bm1, gm, bm, ws);
    outKernel   <<<dim3(1),         dim3(320), 0, stream>>>(Wm2, bm2, ws, out);
}

// Round 4
// 131.920 us; speedup vs baseline: 2.0341x; 1.2919x over previous
//
#include <hip/hip_runtime.h>
#include <float.h>
#include <math.h>

// ---- tuning ----
#define S0 8     // pass0 chunks per segment
#define SB 6     // passB chunks per segment -> 64*6*2 = 768 blocks = 3/CU exact fill

// ---- workspace layout (float offsets); total ~260k floats (~1.04 MB) ----
#define O_BOUNDS 0                 // 2*65 ints (as raw bytes)
#define O_U      160               // 192 folded W1
#define O_W2BF   352               // 1024 dwords = 2048 bf16 (W2 rows 0..31)
#define BR_BASE  1376
#define BRSZ     94336
#define O_CNT    0                 // 64
#define O_BIAS1  64                // 64*32
#define O_AB1    2112              // 64
#define O_P0PART 2176              // 64*S0*28 = 14336
#define O_BPART  16512             // 64*SB*192 = 73728 [srelu32|h1max32|mmsq64|mmmax64]
#define O_PMAX   90240             // 4096
#define O_D      (BR_BASE + 2*BRSZ)   // 65536
#define O_HMLP   (O_D + 65536)        // 4096

typedef __attribute__((ext_vector_type(8))) short short8;
typedef __attribute__((ext_vector_type(4))) float f32x4;

__device__ __forceinline__ int lower_bound_i(const int* a, int n, int v) {
    int lo = 0, hi = n;
    while (lo < hi) { int mid = (lo + hi) >> 1; if (a[mid] < v) lo = mid + 1; else hi = mid; }
    return lo;
}
__device__ __forceinline__ bool is_valid(float p0, float p1) {
    return (floorf((p0 + 3.f) / 6.f) == 0.f) && (floorf((p1 + 3.f) / 6.f) == 0.f);
}
__device__ __forceinline__ unsigned short f2bf(float x) {
    unsigned int u = __float_as_uint(x);
    return (unsigned short)((u + 0x7FFFu + ((u >> 16) & 1u)) >> 16);   // RNE
}

// ---- 65 segment boundaries per branch (kills per-block binary searches) ----
__global__ void segBoundsKernel(const int* __restrict__ bt0, const int* __restrict__ bt1,
                                int N, float* ws) {
    int br = blockIdx.y;
    const int* batch = br ? bt1 : bt0;
    int* bounds = (int*)(ws + O_BOUNDS) + br * 65;
    int t = threadIdx.x;
    if (t <= 64) bounds[t] = lower_bound_i(batch, N, t);
}

// ---- pass0: per-seg cnt + Sum(feat6) + Sum(feat6 feat6^T) over valid points ----
__global__ __launch_bounds__(256) void pass0Kernel(const float* __restrict__ x0,
                                                   const float* __restrict__ x1,
                                                   int N, float* ws) {
    int br = blockIdx.y;
    const float* x = br ? x1 : x0;
    float* base = ws + BR_BASE + (size_t)br * BRSZ;
    const int* bounds = (const int*)(ws + O_BOUNDS) + br * 65;
    int b = blockIdx.x / S0, s = blockIdx.x % S0;
    int lo = bounds[b], hi = bounds[b + 1];
    int chunk = (hi - lo + S0 - 1) / S0;
    int beg = lo + s * chunk, end = min(hi, beg + chunk);

    float acc[28];
    #pragma unroll
    for (int k = 0; k < 28; k++) acc[k] = 0.f;

    for (int i = beg + (int)threadIdx.x; i < end; i += 256) {
        const float2* px = (const float2*)(x + (size_t)i * 6);
        float2 q0 = px[0], q1 = px[1], q2 = px[2];
        float f[6] = {q0.x, q0.y, q1.x, q1.y, q2.x, q2.y};
        if (is_valid(f[0], f[1])) {
            acc[0] += 1.f;
            #pragma unroll
            for (int k = 0; k < 6; k++) acc[1 + k] += f[k];
            int k = 7;
            #pragma unroll
            for (int a = 0; a < 6; a++)
                #pragma unroll
                for (int c = a; c < 6; c++) { acc[k] = fmaf(f[a], f[c], acc[k]); k++; }
        }
    }
    __shared__ float red[4][28];
    int w = threadIdx.x >> 6, l = threadIdx.x & 63;
    #pragma unroll
    for (int k = 0; k < 28; k++) {
        float v = acc[k];
        v += __shfl_xor(v, 1); v += __shfl_xor(v, 2); v += __shfl_xor(v, 4);
        v += __shfl_xor(v, 8); v += __shfl_xor(v, 16); v += __shfl_xor(v, 32);
        acc[k] = v;
    }
    if (l == 0) { for (int k = 0; k < 28; k++) red[w][k] = acc[k]; }
    __syncthreads();
    if (threadIdx.x < 28) {
        float v = red[0][threadIdx.x] + red[1][threadIdx.x] + red[2][threadIdx.x] + red[3][threadIdx.x];
        base[O_P0PART + (size_t)(b * S0 + s) * 28 + threadIdx.x] = v;   // unconditional: no init needed
    }
}

// ---- bn1Coef: U fold, W2->bf16, per-seg bias, analytic BN1 (mean/var from moments) ----
__global__ __launch_bounds__(256) void bn1CoefKernel(const float* __restrict__ W1,
                                                     const float* __restrict__ W2,
                                                     const float* __restrict__ g1,
                                                     const float* __restrict__ bb1, float* ws) {
    int br = blockIdx.y;
    float* base = ws + BR_BASE + (size_t)br * BRSZ;
    int t = threadIdx.x;
    __shared__ float SEG[64][28];
    __shared__ float Ul[6][32];
    __shared__ float C32l[32];
    __shared__ float red[8][32], red2[8][32];

    if (t < 192) {
        int k = t / 32, c = t & 31;
        float u = (k < 3) ? (W1[k*32+c] + W1[(k+3)*32+c] + W1[(k+6)*32+c]) : W1[(k+6)*32+c];
        Ul[k][c] = u;
        ws[O_U + t] = u;                      // both branch-blocks write identical values (benign)
    }
    if (t < 32) C32l[t] = 3.f * (W1[6*32+t] + W1[7*32+t]);
    #pragma unroll
    for (int r = 0; r < 4; r++) {             // W2[:32] -> bf16 (benign dup across branches)
        int idx = t + r * 256;
        unsigned int lo = f2bf(W2[2*idx]), hi = f2bf(W2[2*idx + 1]);
        ((unsigned int*)(ws + O_W2BF))[idx] = lo | (hi << 16);
    }
    #pragma unroll
    for (int r = 0; r < 7; r++) {             // reduce pass0 partials: 64*28 = 1792
        int idx = t + r * 256;
        int b = idx / 28, k = idx % 28;
        float v = 0.f;
        for (int sc = 0; sc < S0; sc++) v += base[O_P0PART + (size_t)(b*S0+sc)*28 + k];
        SEG[b][k] = v;
    }
    __syncthreads();
    if (t < 64) base[O_CNT + t] = SEG[t][0];

    int c = t & 31, bg = t >> 5;
    float ps1 = 0.f, pss = 0.f;
    for (int j = 0; j < 8; j++) {
        int b = bg * 8 + j;
        float cnt = SEG[b][0];
        float cn = fmaxf(cnt, 1.f);
        float bias = C32l[c] - (SEG[b][1]/cn)*W1[3*32+c] - (SEG[b][2]/cn)*W1[4*32+c] - (SEG[b][3]/cn)*W1[5*32+c];
        base[O_BIAS1 + b*32 + c] = bias;
        float dotv = 0.f;
        #pragma unroll
        for (int i = 0; i < 6; i++) dotv = fmaf(SEG[b][1+i], Ul[i][c], dotv);
        float quad = 0.f;
        int k = 7;
        #pragma unroll
        for (int i = 0; i < 6; i++) {
            quad = fmaf(SEG[b][k], Ul[i][c] * Ul[i][c], quad); k++;
            #pragma unroll
            for (int j2 = i + 1; j2 < 6; j2++) { quad = fmaf(SEG[b][k], 2.f * Ul[i][c] * Ul[j2][c], quad); k++; }
        }
        ps1 += dotv + cnt * bias;
        pss += quad + 2.f * bias * dotv + cnt * bias * bias;
    }
    red[bg][c] = ps1; red2[bg][c] = pss;
    __syncthreads();
    if (bg == 0) {
        float s1 = 0.f, sq = 0.f;
        for (int k = 0; k < 8; k++) { s1 += red[k][c]; sq += red2[k][c]; }
        float tot = 0.f;
        for (int k = 0; k < 64; k++) tot += SEG[k][0];
        float n = fmaxf(tot, 1.f);
        float m = s1 / n, v = sq / n - m * m;
        float a = g1[c] * rsqrtf(v + 0.001f);       // NOTE: g1==ones -> a>0 (min-tracking dropped downstream)
        base[O_AB1 + c] = a;
        base[O_AB1 + 32 + c] = bb1[c] - m * a;
    }
}

// ---- passB: pipelined MFMA pass. stage1: h1 fp32 -> relu(bn1) bf16 + srelu + h1max.
//      stage2: mm = A@W2[:32] (MFMA) -> mmsq (zeroed-A, unmasked) + masked mmmax. ----
__global__ __launch_bounds__(256, 3) void passBKernel(const float* __restrict__ x0,
                                                      const float* __restrict__ x1,
                                                      int N, float* ws) {
    int br = blockIdx.y;
    const float* x = br ? x1 : x0;
    float* base = ws + BR_BASE + (size_t)br * BRSZ;
    const int* bounds = (const int*)(ws + O_BOUNDS) + br * 65;
    int b = blockIdx.x / SB, s = blockIdx.x % SB;
    int lo = bounds[b], hi = bounds[b + 1];
    int chunk = (hi - lo + SB - 1) / SB;
    int beg = lo + s * chunk, end = min(hi, beg + chunk);
    int npts = end - beg;
    int ntiles = npts > 0 ? ((npts + 63) >> 6) : 0;

    __shared__ unsigned short Abuf[2][64 * 40];   // bf16 [pt][32ch + 8 pad] (80B rows: 2-way banks)
    __shared__ float flagv[2][64];
    __shared__ float redX[4][64];

    int t = threadIdx.x;
    int ps = t & 31, cg = t >> 5, c4 = cg * 4;    // stage1: 32 pt-slots x 8 ch-groups(4ch)
    int l = t & 63, w = t >> 6, n0 = l & 15, g4 = l >> 4;   // stage2

    const unsigned short* w2u = (const unsigned short*)(ws + O_W2BF);
    short8 bfrag[4];
    #pragma unroll
    for (int ct = 0; ct < 4; ct++)
        #pragma unroll
        for (int j = 0; j < 8; j++)
            bfrag[ct][j] = (short)w2u[(8 * g4 + j) * 64 + 16 * ct + n0];

    float u[4][6], bias[4], a1[4], ab1[4];
    #pragma unroll
    for (int cc = 0; cc < 4; cc++) {
        #pragma unroll
        for (int k = 0; k < 6; k++) u[cc][k] = ws[O_U + k * 32 + c4 + cc];
        bias[cc] = base[O_BIAS1 + b * 32 + c4 + cc];
        a1[cc]   = base[O_AB1 + c4 + cc];
        ab1[cc]  = base[O_AB1 + 32 + c4 + cc];
    }

    float srelu[4] = {0, 0, 0, 0};
    float h1mx[4] = {-FLT_MAX, -FLT_MAX, -FLT_MAX, -FLT_MAX};
    f32x4 sq[4], mx[4];
    #pragma unroll
    for (int ct = 0; ct < 4; ct++) {
        sq[ct] = (f32x4){0, 0, 0, 0};
        mx[ct] = (f32x4){-FLT_MAX, -FLT_MAX, -FLT_MAX, -FLT_MAX};
    }

    float2 xr[2][2][3];
#define LOADX(dst, tk) do { \
        int tb_ = beg + (tk) * 64; \
        _Pragma("unroll") \
        for (int pp_ = 0; pp_ < 2; pp_++) { \
            int idx_ = tb_ + ps + pp_ * 32; \
            if (idx_ < end) { \
                const float2* px_ = (const float2*)(x + (size_t)idx_ * 6); \
                dst[pp_][0] = px_[0]; dst[pp_][1] = px_[1]; dst[pp_][2] = px_[2]; \
            } else { \
                dst[pp_][0] = make_float2(0.f, 0.f); dst[pp_][1] = make_float2(0.f, 0.f); dst[pp_][2] = make_float2(0.f, 0.f); \
            } \
        } } while (0)

    LOADX(xr[0], 0);
    LOADX(xr[1], 1);

    for (int k = 0; k < ntiles; k++) {
        int cur = k & 1;
        int tb = beg + k * 64;
        // ---- stage1 ----
        #pragma unroll
        for (int pp = 0; pp < 2; pp++) {
            int idx = tb + ps + pp * 32;
            int p = ps + pp * 32;
            float2 q0 = xr[cur][pp][0], q1 = xr[cur][pp][1], q2 = xr[cur][pp][2];
            float p0 = q0.x, p1 = q0.y, p2 = q1.x, e0 = q1.y, e1 = q2.x, e2 = q2.y;
            bool val = (idx < end) && is_valid(p0, p1);
            float rr[4];
            #pragma unroll
            for (int cc = 0; cc < 4; cc++) {
                float h = fmaf(p0, u[cc][0], fmaf(p1, u[cc][1], fmaf(p2, u[cc][2],
                          fmaf(e0, u[cc][3], fmaf(e1, u[cc][4], fmaf(e2, u[cc][5], bias[cc]))))));
                float r = fmaxf(fmaf(a1[cc], h, ab1[cc]), 0.f);
                r = val ? r : 0.f;                       // zeroed A-row for invalid/oob
                rr[cc] = r;
                srelu[cc] += r;
                h1mx[cc] = fmaxf(h1mx[cc], val ? h : -FLT_MAX);
            }
            unsigned int pk0 = (unsigned int)f2bf(rr[0]) | ((unsigned int)f2bf(rr[1]) << 16);
            unsigned int pk1 = (unsigned int)f2bf(rr[2]) | ((unsigned int)f2bf(rr[3]) << 16);
            *(uint2*)&Abuf[cur][p * 40 + c4] = make_uint2(pk0, pk1);
            if (cg == 0) flagv[cur][p] = val ? 1.f : 0.f;
        }
        LOADX(xr[cur], k + 2);      // prefetch 2 tiles ahead; in flight across barrier
        __syncthreads();
        // ---- stage2 ----
        short8 af = *(const short8*)&Abuf[cur][(16 * w + n0) * 40 + g4 * 8];
        f32x4 fl4 = *(const f32x4*)&flagv[cur][16 * w + 4 * g4];
        #pragma unroll
        for (int ct = 0; ct < 4; ct++) {
            f32x4 cz = (f32x4){0, 0, 0, 0};
            f32x4 v = __builtin_amdgcn_mfma_f32_16x16x32_bf16(af, bfrag[ct], cz, 0, 0, 0);
            #pragma unroll
            for (int r = 0; r < 4; r++) {
                sq[ct][r] = fmaf(v[r], v[r], sq[ct][r]);            // invalid rows give v==0
                mx[ct][r] = fmaxf(mx[ct][r], (fl4[r] != 0.f) ? v[r] : -FLT_MAX);
            }
        }
    }

    // ---- epilogue: per-block partials (non-atomic, unconditional) ----
    float* part = base + O_BPART + (size_t)(b * SB + s) * 192;
    float sqc[4], mxc[4];
    #pragma unroll
    for (int ct = 0; ct < 4; ct++) {
        float sv = sq[ct][0] + sq[ct][1] + sq[ct][2] + sq[ct][3];
        float mv = fmaxf(fmaxf(mx[ct][0], mx[ct][1]), fmaxf(mx[ct][2], mx[ct][3]));
        sv += __shfl_xor(sv, 16); sv += __shfl_xor(sv, 32);
        mv = fmaxf(mv, __shfl_xor(mv, 16)); mv = fmaxf(mv, __shfl_xor(mv, 32));
        sqc[ct] = sv; mxc[ct] = mv;
    }
    __syncthreads();
    if (l < 16) { for (int ct = 0; ct < 4; ct++) redX[w][16 * ct + l] = sqc[ct]; }
    __syncthreads();
    if (w == 0) part[64 + l] = redX[0][l] + redX[1][l] + redX[2][l] + redX[3][l];
    __syncthreads();
    if (l < 16) { for (int ct = 0; ct < 4; ct++) redX[w][16 * ct + l] = mxc[ct]; }
    __syncthreads();
    if (w == 0) part[128 + l] = fmaxf(fmaxf(redX[0][l], redX[1][l]), fmaxf(redX[2][l], redX[3][l]));
    #pragma unroll
    for (int cc = 0; cc < 4; cc++) {
        float sv = srelu[cc], hv = h1mx[cc];
        sv += __shfl_xor(sv, 1); sv += __shfl_xor(sv, 2); sv += __shfl_xor(sv, 4);
        sv += __shfl_xor(sv, 8); sv += __shfl_xor(sv, 16);
        hv = fmaxf(hv, __shfl_xor(hv, 1)); hv = fmaxf(hv, __shfl_xor(hv, 2));
        hv = fmaxf(hv, __shfl_xor(hv, 4)); hv = fmaxf(hv, __shfl_xor(hv, 8));
        hv = fmaxf(hv, __shfl_xor(hv, 16));
        if (ps == 0) { part[c4 + cc] = sv; part[32 + c4 + cc] = hv; }
    }
#undef LOADX
}

// ---- segFuse: hseg + analytic BN2 + pmax (replaces 3 kernels) ----
__global__ __launch_bounds__(256) void segFuseKernel(const float* __restrict__ W2,
                                                     const float* __restrict__ g2,
                                                     const float* __restrict__ bb2, float* ws) {
    int br = blockIdx.y;
    float* base = ws + BR_BASE + (size_t)br * BRSZ;
    int t = threadIdx.x;
    __shared__ float HM[64][32], SR[64][32];
    __shared__ float W2a[32][64], W2b[32][64];
    __shared__ float HS[64][64];
    __shared__ float CNTl[64];
    __shared__ float redS[4][64], redQ[4][64];
    __shared__ float AB2[2][64];

    #pragma unroll
    for (int r = 0; r < 8; r++) {
        int idx = t + r * 256;
        ((float*)W2a)[idx] = W2[idx];
        ((float*)W2b)[idx] = W2[2048 + idx];
    }
    if (t < 64) CNTl[t] = base[O_CNT + t];
    #pragma unroll
    for (int r = 0; r < 8; r++) {                 // 64*32: reduce srelu + h1max, compute hm
        int idx = t + r * 256;
        int b = idx >> 5, c = idx & 31;
        float sv = 0.f, hv = -FLT_MAX;
        for (int sc = 0; sc < SB; sc++) {
            const float* part = base + O_BPART + (size_t)(b * SB + sc) * 192;
            sv += part[c];
            hv = fmaxf(hv, part[32 + c]);
        }
        SR[b][c] = sv;
        float a = base[O_AB1 + c], ab = base[O_AB1 + 32 + c];
        HM[b][c] = fmaxf(fmaf(a, hv, ab), 0.f);   // empty seg: -inf -> relu 0 (matches ref)
    }
    __syncthreads();
    int col = t & 63, bgq = t >> 6;
    float S = 0.f, Q = 0.f;
    for (int j = 0; j < 16; j++) {
        int b = bgq * 16 + j;
        float hs = 0.f, smm = 0.f;
        #pragma unroll
        for (int ch = 0; ch < 32; ch++) {
            hs  = fmaf(HM[b][ch], W2b[ch][col], hs);
            smm = fmaf(SR[b][ch], W2a[ch][col], smm);
        }
        HS[b][col] = hs;
        float cnt = CNTl[b];
        float qb = 0.f;
        const float* part = base + O_BPART + (size_t)(b * SB) * 192;
        for (int sc = 0; sc < SB; sc++) qb += part[sc * 192 + 64 + col];
        S += smm + cnt * hs;
        Q += qb + 2.f * hs * smm + cnt * hs * hs;
    }
    redS[bgq][col] = S; redQ[bgq][col] = Q;
    __syncthreads();
    if (t < 64) {
        float Sv = redS[0][t] + redS[1][t] + redS[2][t] + redS[3][t];
        float Qv = redQ[0][t] + redQ[1][t] + redQ[2][t] + redQ[3][t];
        float tot = 0.f;
        for (int k = 0; k < 64; k++) tot += CNTl[k];
        float n = fmaxf(tot, 1.f);
        float m = Sv / n, v = Qv / n - m * m;
        float a = g2[t] * rsqrtf(v + 0.001f);     // g2==ones -> a>0
        AB2[0][t] = a; AB2[1][t] = bb2[t] - m * a;
    }
    __syncthreads();
    #pragma unroll
    for (int r = 0; r < 16; r++) {                // 64*64 pmax
        int idx = t + r * 256;
        int b = idx >> 6, c2 = idx & 63;
        float mv = -FLT_MAX;
        const float* part = base + O_BPART + (size_t)(b * SB) * 192;
        for (int sc = 0; sc < SB; sc++) mv = fmaxf(mv, part[sc * 192 + 128 + c2]);
        float out = 0.f;
        if (CNTl[b] > 0.f) out = fmaxf(fmaf(AB2[0][c2], mv + HS[b][c2], AB2[1][c2]), 0.f);
        base[O_PMAX + b * 64 + c2] = out;
    }
}

// ---- d = relu(bn(p2@Wc^T)) - relu(bn(p1@Wc^T)) ----
__global__ void dKernel(const float* __restrict__ Wc, const float* __restrict__ gc,
                        const float* __restrict__ bc, float* ws) {
    int j = blockIdx.x, i = threadIdx.x;
    const float* p1 = ws + BR_BASE + O_PMAX;
    const float* p2 = ws + BR_BASE + BRSZ + O_PMAX;
    float t1 = 0.f, t2 = 0.f;
    for (int c = 0; c < 64; c++) {
        float wc = Wc[(size_t)j * 64 + c];
        t1 = fmaf(p1[i * 64 + c], wc, t1);
        t2 = fmaf(p2[i * 64 + c], wc, t2);
    }
    float m1 = t1, m2 = t2;
    for (int off = 32; off; off >>= 1) { m1 += __shfl_xor(m1, off); m2 += __shfl_xor(m2, off); }
    m1 *= (1.f / 64.f); m2 *= (1.f / 64.f);
    float d1 = t1 - m1, d2 = t2 - m2;
    float v1 = d1 * d1, v2 = d2 * d2;
    for (int off = 32; off; off >>= 1) { v1 += __shfl_xor(v1, off); v2 += __shfl_xor(v2, off); }
    v1 *= (1.f / 64.f); v2 *= (1.f / 64.f);
    float z1 = fmaxf(d1 * rsqrtf(v1 + 0.001f) * gc[j] + bc[j], 0.f);
    float z2 = fmaxf(d2 * rsqrtf(v2 + 0.001f) * gc[j] + bc[j], 0.f);
    ws[O_D + (size_t)i * 1024 + j] = z2 - z1;
}

// ---- h = bn(relu(d @ Wm1 + bm1)) ----
__global__ __launch_bounds__(256) void hKernel(const float* __restrict__ Wm1, const float* __restrict__ bm1,
                                               const float* __restrict__ gm, const float* __restrict__ bm,
                                               float* ws) {
    int cidx = blockIdx.x;
    int t = threadIdx.x;
    int i = t & 63, q = t >> 6;
    const float* d = ws + O_D;
    float partv = 0.f;
    for (int k = q * 256; k < q * 256 + 256; k++)
        partv = fmaf(d[(size_t)i * 1024 + k], Wm1[(size_t)k * 64 + cidx], partv);
    __shared__ float red[4][64];
    red[q][i] = partv; __syncthreads();
    if (t < 64) {
        float u = red[0][i] + red[1][i] + red[2][i] + red[3][i] + bm1[cidx];
        u = fmaxf(u, 0.f);
        float m = u;
        for (int off = 32; off; off >>= 1) m += __shfl_xor(m, off);
        m *= (1.f / 64.f);
        float du = u - m;
        float v = du * du;
        for (int off = 32; off; off >>= 1) v += __shfl_xor(v, off);
        v *= (1.f / 64.f);
        ws[O_HMLP + (size_t)i * 64 + cidx] = du * rsqrtf(v + 1e-5f) * gm[cidx] + bm[cidx];
    }
}

__global__ void outKernel(const float* __restrict__ Wm2, const float* __restrict__ bm2,
                          const float* __restrict__ ws, float* out) {
    __shared__ float lg[64][5];
    __shared__ float lse[64];
    int t = threadIdx.x;   // 320
    {
        int i = t / 5, j = t % 5;
        const float* h = ws + O_HMLP;
        float acc = bm2[j];
        for (int k = 0; k < 64; k++) acc = fmaf(h[i * 64 + k], Wm2[k * 5 + j], acc);
        lg[i][j] = acc;
    }
    __syncthreads();
    if (t < 64) {
        float mxv = lg[t][0];
        for (int j = 1; j < 5; j++) mxv = fmaxf(mxv, lg[t][j]);
        float sv = 0.f;
        for (int j = 0; j < 5; j++) sv += expf(lg[t][j] - mxv);
        lse[t] = mxv + logf(sv);
    }
    __syncthreads();
    out[t] = lg[t / 5][t % 5] - lse[t / 5];
}

extern "C" void kernel_launch(void* const* d_in, const int* in_sizes, int n_in,
                              void* d_out, int out_size, void* d_ws, size_t ws_size,
                              hipStream_t stream) {
    const float* x0  = (const float*)d_in[0];
    const float* x1  = (const float*)d_in[1];
    const int*   bt0 = (const int*)d_in[2];
    const int*   bt1 = (const int*)d_in[3];
    const float* W1  = (const float*)d_in[5];
    const float* g1  = (const float*)d_in[6];
    const float* bb1 = (const float*)d_in[7];
    const float* W2  = (const float*)d_in[8];
    const float* g2  = (const float*)d_in[9];
    const float* bb2 = (const float*)d_in[10];
    const float* Wc  = (const float*)d_in[11];
    const float* gc  = (const float*)d_in[12];
    const float* bc  = (const float*)d_in[13];
    const float* Wm1 = (const float*)d_in[14];
    const float* bm1 = (const float*)d_in[15];
    const float* gm  = (const float*)d_in[16];
    const float* bm  = (const float*)d_in[17];
    const float* Wm2 = (const float*)d_in[18];
    const float* bm2 = (const float*)d_in[19];
    float* ws  = (float*)d_ws;
    float* out = (float*)d_out;
    int N = in_sizes[0] / 6;

    segBoundsKernel<<<dim3(1, 2),      dim3(128), 0, stream>>>(bt0, bt1, N, ws);
    pass0Kernel    <<<dim3(64*S0, 2),  dim3(256), 0, stream>>>(x0, x1, N, ws);
    bn1CoefKernel  <<<dim3(1, 2),      dim3(256), 0, stream>>>(W1, W2, g1, bb1, ws);
    passBKernel    <<<dim3(64*SB, 2),  dim3(256), 0, stream>>>(x0, x1, N, ws);
    segFuseKernel  <<<dim3(1, 2),      dim3(256), 0, stream>>>(W2, g2, bb2, ws);
    dKernel        <<<dim3(1024),      dim3(64),  0, stream>>>(Wc, gc, bc, ws);
    hKernel        <<<dim3(64),        dim3(256), 0, stream>>>(Wm1, bm1, gm, bm, ws);
    outKernel      <<<dim3(1),         dim3(320), 0, stream>>>(Wm2, bm2, ws, out);
}